// Round 6
// baseline (3308.004 us; speedup 1.0000x reference)
//
#include <hip/hip_runtime.h>

typedef unsigned short u16;
typedef unsigned int u32;
typedef unsigned long long u64;
typedef short v8s __attribute__((ext_vector_type(8)));
typedef float v4f __attribute__((ext_vector_type(4)));

// Dims: B=256, T=512, D=32, H=256, 4H=1024, A=128, HOR=24, NQ=3
// 256 blocks = 16 groups (16 batch rows) x 16 slices (16 units = 64 gate-cols).
// Weights in registers as MFMA B-frags. Exchange protocol: plain-value data
// stores (relaxed agent atomics) -> __syncthreads (vmcnt drained) -> one
// sentinel word per block. Readers poll ONE sentinel each, then burst-load
// data once (no retry) -> ~250x less poll traffic than tag-in-data (R5).

__device__ __forceinline__ float bf2f(u16 u) { union { u32 u; float f; } c; c.u = ((u32)u) << 16; return c.f; }
__device__ __forceinline__ u16 f2bf(float f) {
  union { float f; u32 u; } c; c.f = f;
  u32 r = c.u + 0x7FFFu + ((c.u >> 16) & 1u);   // RTNE
  return (u16)(r >> 16);
}
__device__ __forceinline__ float sigf(float x) { return 1.f / (1.f + __expf(-x)); }
__device__ __forceinline__ float tanhfast(float x) {
  x = fminf(15.f, fmaxf(-15.f, x));
  float e = __expf(2.f * x);
  return (e - 1.f) / (e + 1.f);
}
__device__ __forceinline__ float ldIn(const void* p, size_t i, int isbf) {
  return isbf ? bf2f(((const u16*)p)[i]) : ((const float*)p)[i];
}
__device__ __forceinline__ v8s ld8hi(const void* p, size_t e, int isbf) {
  if (isbf) return *(const v8s*)((const u16*)p + e);
  const float* f = (const float*)p + e;
  v8s r;
#pragma unroll
  for (int j = 0; j < 8; ++j) r[j] = (short)f2bf(f[j]);
  return r;
}
__device__ __forceinline__ void ld8split(const void* p, size_t e, int isbf, v8s& hi, v8s& lo) {
  if (isbf) {
    hi = *(const v8s*)((const u16*)p + e);
    lo = v8s{0, 0, 0, 0, 0, 0, 0, 0};
  } else {
    const float* f = (const float*)p + e;
#pragma unroll
    for (int j = 0; j < 8; ++j) {
      u16 h = f2bf(f[j]);
      hi[j] = (short)h;
      lo[j] = (short)f2bf(f[j] - bf2f(h));
    }
  }
}
#define MFMA(a, b, c) __builtin_amdgcn_mfma_f32_16x16x32_bf16(a, b, c, 0, 0, 0)

__device__ __forceinline__ u64 aload64(const u64* p) {
  return __hip_atomic_load(p, __ATOMIC_RELAXED, __HIP_MEMORY_SCOPE_AGENT);
}
__device__ __forceinline__ int aloadi(const int* p) {
  return __hip_atomic_load(p, __ATOMIC_RELAXED, __HIP_MEMORY_SCOPE_AGENT);
}
__device__ __forceinline__ void astorei(int* p, int v) {
  __hip_atomic_store(p, v, __ATOMIC_RELAXED, __HIP_MEMORY_SCOPE_AGENT);
}
__device__ __forceinline__ void astore16(u16* p, u16 v) {
  __hip_atomic_store(p, v, __ATOMIC_RELAXED, __HIP_MEMORY_SCOPE_AGENT);
}
__device__ __forceinline__ void astore32(u32* p, u32 v) {
  __hip_atomic_store(p, v, __ATOMIC_RELAXED, __HIP_MEMORY_SCOPE_AGENT);
}
__device__ __forceinline__ void astore64(u64* p, u64 v) {
  __hip_atomic_store(p, v, __ATOMIC_RELAXED, __HIP_MEMORY_SCOPE_AGENT);
}

// ---- Encoder stage: poll one sentinel (this thread's data slice), then
// burst-load u64 quads of h0/h1 (u16 values, [16 rows][256 units]).
// Thread's quads: rows {4i + tid>>6}, units 4*(tid&63).. -> slice (tid&63)>>2.
__device__ __forceinline__ void stage_encS(u16* h0s, u16* h1s,
                                           const u16* s0, const u16* s1,
                                           const int* sent, int expv,
                                           int tid, bool doH0) {
  const int* sp = sent + ((tid & 63) >> 2);
  while (aloadi(sp) < expv) {}
  const u64* p0 = (const u64*)s0;
  const u64* p1 = (const u64*)s1;
  const int c8 = tid & 63;
#pragma unroll
  for (int i = 0; i < 4; ++i) {
    int w = i * 256 + tid;
    int row = (w >> 6);
    *(u64*)(h1s + row * 264 + c8 * 4) = aload64(p1 + w);
    if (doH0) *(u64*)(h0s + row * 264 + c8 * 4) = aload64(p0 + w);
  }
}

// ---- Decoder: poll slice sentinel; data u32/unit = hi|lo<<16, [16][256] u32
// viewed [16][128] u64. Thread's quads: rows {2i + tid>>7}, units 2*(tid&127)..
// -> slice (tid&127)>>3.
__device__ __forceinline__ void poll_dec(const int* sent, int expv, int tid) {
  const int* sp = sent + ((tid & 127) >> 3);
  while (aloadi(sp) < expv) {}
}
__device__ __forceinline__ void ldsput_u32(u16* dhi, u16* dlo, const u64* src, int tid) {
  const int col = tid & 127;
#pragma unroll
  for (int i = 0; i < 8; ++i) {
    int row = 2 * i + (tid >> 7);
    u64 w = aload64(src + i * 256 + tid);
    ((u32*)(dhi + row * 264))[col] = (u32)(u16)w | ((u32)(u16)(w >> 32) << 16);
    ((u32*)(dlo + row * 264))[col] = (u32)(u16)(w >> 16) | ((u32)(u16)(w >> 48) << 16);
  }
}
__device__ __forceinline__ void stage_f32(u16* dhi, u16* dlo, const float* src, int tid) {
#pragma unroll
  for (int i = 0; i < 8; ++i) {
    int e = i * 512 + tid * 2;
    int row = e >> 8, jc = e & 255;
    float f0 = src[row * 256 + jc], f1 = src[row * 256 + jc + 1];
    u16 h0 = f2bf(f0), h1 = f2bf(f1);
    u16 l0 = f2bf(f0 - bf2f(h0)), l1 = f2bf(f1 - bf2f(h1));
    ((u32*)(dhi + row * 264))[jc >> 1] = (u32)h0 | ((u32)h1 << 16);
    ((u32*)(dlo + row * 264))[jc >> 1] = (u32)l0 | ((u32)l1 << 16);
  }
}

__global__ void sniff_kernel(const u16* __restrict__ w, int* __restrict__ flag) {
  __shared__ int cnt;
  if (threadIdx.x == 0) cnt = 0;
  __syncthreads();
  int ok = 0;
  for (int i = threadIdx.x; i < 1024; i += 256) {
    u16 u = w[2 * i];
    int e = (u >> 7) & 0xFF;
    ok += (u == 0 || (e >= 97 && e <= 140)) ? 1 : 0;
  }
  atomicAdd(&cnt, ok);
  __syncthreads();
  if (threadIdx.x == 0) *flag = (cnt >= 768) ? 1 : 0;
}

// ---------------- Encoder (both LSTM layers, pipelined) + fused online attention ---
__global__ __launch_bounds__(256, 1) void enc_kernel(
    const void* __restrict__ x,
    const void* __restrict__ eWih0, const void* __restrict__ eWhh0, const void* __restrict__ eb0,
    const void* __restrict__ eWih1, const void* __restrict__ eWhh1, const void* __restrict__ eb1,
    const void* __restrict__ aW, const void* __restrict__ aV,
    u16* __restrict__ H0, u16* __restrict__ H1,
    float* __restrict__ ctx, int* __restrict__ sentE, const int* __restrict__ flagp) {
  __shared__ u16 h0s[16 * 264], h1s[16 * 264];
  __shared__ float gb0[16 * 64], gb1[16 * 64];
  __shared__ float eP[16 * 132];

  const int isbf = *flagp;
  const int tid = threadIdx.x, blk = blockIdx.x;
  const int grp = blk & 15, gs = blk >> 4;
  const int lane = tid & 63, wv = tid >> 6;      // wave = gate index
  const int ln = lane & 15, lq = lane >> 4;

  v8s W0F[9], W1F[16], AWF[16];
  {
    const int gw = wv * 256 + gs * 16 + ln;
    const int kq = lq * 8;
    W0F[0] = ld8hi(eWih0, (size_t)gw * 32 + kq, isbf);
#pragma unroll
    for (int kt = 0; kt < 8; ++kt) {
      W0F[kt + 1] = ld8hi(eWhh0, (size_t)gw * 256 + kt * 32 + kq, isbf);
      W1F[kt]     = ld8hi(eWhh1, (size_t)gw * 256 + kt * 32 + kq, isbf);
      W1F[kt + 8] = ld8hi(eWih1, (size_t)gw * 256 + kt * 32 + kq, isbf);
    }
#pragma unroll
    for (int kt = 0; kt < 8; ++kt)
#pragma unroll
      for (int j2 = 0; j2 < 2; ++j2) {
        v8s f;
        int ac = (2 * wv + j2) * 16 + ln;
#pragma unroll
        for (int j = 0; j < 8; ++j)
          f[j] = (short)f2bf(ldIn(aW, (size_t)(kt * 32 + kq + j) * 128 + ac, isbf));
        AWF[kt * 2 + j2] = f;
      }
  }

  const int urow = tid >> 4, uu = tid & 15;
  float bg0[4], bg1[4], aVr[8];
#pragma unroll
  for (int g = 0; g < 4; ++g) {
    bg0[g] = ldIn(eb0, g * 256 + gs * 16 + uu, isbf);
    bg1[g] = ldIn(eb1, g * 256 + gs * 16 + uu, isbf);
  }
#pragma unroll
  for (int j = 0; j < 8; ++j) aVr[j] = ldIn(aV, (size_t)(uu + 16 * j), isbf);

  const int gRowU = grp * 16 + urow;
  const int gUnit = gs * 16 + uu;
  const int aRow = grp * 16 + ln;

  float c0 = 0.f, c1 = 0.f;
  float mS = -3e38f, lS = 0.f, ctxA = 0.f;
  int* sentG = sentE + grp * 16;

  v8s xh_c, xl_c;
  ld8split(x, ((size_t)aRow * 512) * 32 + lq * 8, isbf, xh_c, xl_c);

  // t: L0 -> h0[t]; L1 -> h1[t-1]; attn+ctx consume h1[t-2]
#pragma unroll 1
  for (int t = 0; t < 514; ++t) {
    const int rB = (t + 1) & 1, wB = t & 1;
    // poll sentinel >= t, then burst-load h0[t-1] (parity rB) & h1[t-2] (parity wB)
    stage_encS(h0s, h1s,
               H0 + (size_t)rB * 65536 + grp * 4096,
               H1 + (size_t)wB * 65536 + grp * 4096,
               sentG, t, tid, t <= 512);
    v8s xh_n, xl_n;
    {
      int tn = (t + 1 < 512) ? t + 1 : 511;
      ld8split(x, ((size_t)aRow * 512 + tn) * 32 + lq * 8, isbf, xh_n, xl_n);
    }
    __syncthreads();   // sync1: staging complete

    v4f acc0 = {0, 0, 0, 0}, acc1 = {0, 0, 0, 0}, accA0 = {0, 0, 0, 0}, accA1 = {0, 0, 0, 0};
    acc0 = MFMA(xh_c, W0F[0], acc0);
    if (!isbf) acc0 = MFMA(xl_c, W0F[0], acc0);
#pragma unroll
    for (int kt = 0; kt < 8; ++kt) {
      const int off = ln * 264 + kt * 32 + lq * 8;
      v8s a0 = *(const v8s*)(h0s + off);
      acc0 = MFMA(a0, W0F[kt + 1], acc0);
      acc1 = MFMA(a0, W1F[kt + 8], acc1);
      v8s a1 = *(const v8s*)(h1s + off);
      acc1 = MFMA(a1, W1F[kt], acc1);
      accA0 = MFMA(a1, AWF[kt * 2], accA0);
      accA1 = MFMA(a1, AWF[kt * 2 + 1], accA1);
    }
    {
      const int bR = lq * 4;
#pragma unroll
      for (int r = 0; r < 4; ++r) {
        gb0[(bR + r) * 64 + ln * 4 + wv] = acc0[r];
        gb1[(bR + r) * 64 + ln * 4 + wv] = acc1[r];
        eP[(bR + r) * 132 + (2 * wv) * 16 + ln] = accA0[r];
        eP[(bR + r) * 132 + (2 * wv + 1) * 16 + ln] = accA1[r];
      }
    }
    float h1v = bf2f(h1s[urow * 264 + gUnit]);   // hoisted: h1s not read after sync2
    __syncthreads();   // sync2

    if (t < 512) {
      const float* g0 = gb0 + (urow * 16 + uu) * 4;
      float gi = g0[0] + bg0[0], gf = g0[1] + bg0[1], gg = g0[2] + bg0[2], go = g0[3] + bg0[3];
      c0 = sigf(gf) * c0 + sigf(gi) * tanhfast(gg);
      float h = sigf(go) * tanhfast(c0);
      astore16(H0 + (size_t)wB * 65536 + gRowU * 256 + gUnit, f2bf(h));
    }
    if (t >= 1 && t < 513) {
      const float* g1 = gb1 + (urow * 16 + uu) * 4;
      float gi = g1[0] + bg1[0], gf = g1[1] + bg1[1], gg = g1[2] + bg1[2], go = g1[3] + bg1[3];
      c1 = sigf(gf) * c1 + sigf(gi) * tanhfast(gg);
      float h = sigf(go) * tanhfast(c1);
      astore16(H1 + (size_t)rB * 65536 + gRowU * 256 + gUnit, f2bf(h));
    }
    if (t >= 2) {
      float e = 0.f;
#pragma unroll
      for (int j = 0; j < 8; ++j)
        e += tanhfast(eP[urow * 132 + uu + 16 * j]) * aVr[j];
      e += __shfl_xor(e, 1);
      e += __shfl_xor(e, 2);
      e += __shfl_xor(e, 4);
      e += __shfl_xor(e, 8);
      float nm = fmaxf(mS, e);
      float al = __expf(mS - nm), p = __expf(e - nm);
      lS = lS * al + p;
      ctxA = ctxA * al + p * h1v;
      mS = nm;
    }
    xh_c = xh_n; xl_c = xl_n;
    __syncthreads();   // sync3: all waves' stores drained (vmcnt) before publish
    if (tid == 0 && t <= 512) astorei(sentG + gs, t + 1);
  }
  ctx[(size_t)gRowU * 256 + gUnit] = ctxA / lS;
}

// ---------------- Decoder: 24 steps x 2 sub-steps + projection --------------------
__global__ __launch_bounds__(256, 1) void dec_kernel(
    const void* __restrict__ x,
    const void* __restrict__ dWih0, const void* __restrict__ dWhh0, const void* __restrict__ db0,
    const void* __restrict__ dWih1, const void* __restrict__ dWhh1, const void* __restrict__ db1,
    const void* __restrict__ qW, const void* __restrict__ qb,
    const float* __restrict__ ctx,
    u32* __restrict__ H0d, u32* __restrict__ H1d, u64* __restrict__ dinpG,
    void* __restrict__ out, int* __restrict__ sentD, const int* __restrict__ flagp) {
  __shared__ u16 sAhi[16 * 264], sAlo[16 * 264], sBhi[16 * 264], sBlo[16 * 264];
  __shared__ float gb[16 * 64];
  __shared__ float dinpS[16];

  const int isbf = *flagp;
  const int tid = threadIdx.x, blk = blockIdx.x;
  const int grp = blk & 15, gs = blk >> 4;
  const int lane = tid & 63, wv = tid >> 6;
  const int ln = lane & 15, lq = lane >> 4;

  v8s W0F[8], W1F[16];
  {
    const int gw = wv * 256 + gs * 16 + ln;
    const int kq = lq * 8;
#pragma unroll
    for (int kt = 0; kt < 8; ++kt) {
      W0F[kt]     = ld8hi(dWhh0, (size_t)gw * 256 + kt * 32 + kq, isbf);
      W1F[kt]     = ld8hi(dWhh1, (size_t)gw * 256 + kt * 32 + kq, isbf);
      W1F[kt + 8] = ld8hi(dWih1, (size_t)gw * 256 + kt * 32 + kq, isbf);
    }
  }
  const int urow = tid >> 4, uu = tid & 15;
  float bg0[4], bg1[4], w0v[4];
#pragma unroll
  for (int g = 0; g < 4; ++g) {
    bg0[g] = ldIn(db0, g * 256 + gs * 16 + uu, isbf);
    bg1[g] = ldIn(db1, g * 256 + gs * 16 + uu, isbf);
    w0v[g] = ldIn(dWih0, g * 256 + gs * 16 + uu, isbf);
  }
  const int gRowU = grp * 16 + urow;
  const int gUnit = gs * 16 + uu;

  float c0 = ctx[(size_t)gRowU * 256 + gUnit];
  float c1 = c0;
  int* sentG = sentD + grp * 16;

#pragma unroll 1
  for (int t = 0; t < 24; ++t) {
    const int pPrev = (t + 1) & 1, pCur = t & 1;
    // ---- sub-step A: layer-0 cell ----
    if (t == 0) {
      stage_f32(sAhi, sAlo, ctx + (size_t)grp * 16 * 256, tid);
      if (tid < 16)
        dinpS[tid] = ldIn(x, ((size_t)(grp * 16 + tid) * 512 + 511) * 32 + 31, isbf);
    } else {
      poll_dec(sentG, 2 * t - 1, tid);
      ldsput_u32(sAhi, sAlo, (const u64*)(H0d + (size_t)pPrev * 65536 + grp * 4096), tid);
      if (tid < 16) {
        u64 w;
        do { w = aload64(dinpG + pPrev * 256 + grp * 16 + tid); } while ((u32)(w >> 32) != (u32)(2 * t));
        dinpS[tid] = __uint_as_float((u32)w);
      }
    }
    __syncthreads();
    v4f acc = {0, 0, 0, 0};
#pragma unroll
    for (int kt = 0; kt < 8; ++kt) {
      const int off = ln * 264 + kt * 32 + lq * 8;
      acc = MFMA(*(const v8s*)(sAhi + off), W0F[kt], acc);
      acc = MFMA(*(const v8s*)(sAlo + off), W0F[kt], acc);
    }
    {
      const int bR = lq * 4;
#pragma unroll
      for (int r = 0; r < 4; ++r) gb[(bR + r) * 64 + ln * 4 + wv] = acc[r];
    }
    float di = dinpS[urow];   // hoisted
    __syncthreads();
    {
      const float* g0 = gb + (urow * 16 + uu) * 4;
      float gi = g0[0] + bg0[0] + di * w0v[0];
      float gf = g0[1] + bg0[1] + di * w0v[1];
      float gg = g0[2] + bg0[2] + di * w0v[2];
      float go = g0[3] + bg0[3] + di * w0v[3];
      c0 = sigf(gf) * c0 + sigf(gi) * tanhfast(gg);
      float h = sigf(go) * tanhfast(c0);
      u16 hh = f2bf(h); u16 hl = f2bf(h - bf2f(hh));
      astore32(H0d + (size_t)pCur * 65536 + gRowU * 256 + gUnit, (u32)hh | ((u32)hl << 16));
    }
    __syncthreads();   // drain stores
    if (tid == 0) astorei(sentG + gs, 2 * t + 1);
    // ---- sub-step B: layer-1 cell ----
    poll_dec(sentG, 2 * t + 1, tid);   // covers H1d (>=2t) and H0d subA (2t+1)
    if (t == 0) stage_f32(sBhi, sBlo, ctx + (size_t)grp * 16 * 256, tid);
    else ldsput_u32(sBhi, sBlo, (const u64*)(H1d + (size_t)pPrev * 65536 + grp * 4096), tid);
    ldsput_u32(sAhi, sAlo, (const u64*)(H0d + (size_t)pCur * 65536 + grp * 4096), tid);
    __syncthreads();
    v4f a1 = {0, 0, 0, 0};
#pragma unroll
    for (int kt = 0; kt < 8; ++kt) {
      const int off = ln * 264 + kt * 32 + lq * 8;
      a1 = MFMA(*(const v8s*)(sBhi + off), W1F[kt], a1);
      a1 = MFMA(*(const v8s*)(sBlo + off), W1F[kt], a1);
      a1 = MFMA(*(const v8s*)(sAhi + off), W1F[kt + 8], a1);
      a1 = MFMA(*(const v8s*)(sAlo + off), W1F[kt + 8], a1);
    }
    {
      const int bR = lq * 4;
#pragma unroll
      for (int r = 0; r < 4; ++r) gb[(bR + r) * 64 + ln * 4 + wv] = a1[r];
    }
    __syncthreads();
    {
      const float* g1 = gb + (urow * 16 + uu) * 4;
      float gi = g1[0] + bg1[0], gf = g1[1] + bg1[1], gg = g1[2] + bg1[2], go = g1[3] + bg1[3];
      c1 = sigf(gf) * c1 + sigf(gi) * tanhfast(gg);
      float h = sigf(go) * tanhfast(c1);
      u16 hh = f2bf(h); u16 hl = f2bf(h - bf2f(hh));
      astore32(H1d + (size_t)pCur * 65536 + gRowU * 256 + gUnit, (u32)hh | ((u32)hl << 16));
      if (gUnit == 0)
        astore64(dinpG + pCur * 256 + gRowU,
                 (u64)__float_as_uint(h) | ((u64)(u32)(2 * t + 2) << 32));
    }
    __syncthreads();   // drain stores
    if (tid == 0) astorei(sentG + gs, 2 * t + 2);
  }
  // projection: poll >=48, stage h1d[23] (parity 1), compute
  poll_dec(sentG, 48, tid);
  ldsput_u32(sAhi, sAlo, (const u64*)(H1d + (size_t)65536 + grp * 4096), tid);
  __syncthreads();
  if (gs < 12 && tid < 96) {
    int r = tid / 6, p = tid % 6;
    int qo = gs * 6 + p, row = grp * 16 + r;
    float s = ldIn(qb, qo, isbf);
    for (int h = 0; h < 256; ++h)
      s += (bf2f(sAhi[r * 264 + h]) + bf2f(sAlo[r * 264 + h])) * ldIn(qW, (size_t)qo * 256 + h, isbf);
    if (isbf) ((u16*)out)[row * 72 + qo] = f2bf(s);
    else      ((float*)out)[row * 72 + qo] = s;
  }
}

extern "C" void kernel_launch(void* const* d_in, const int* in_sizes, int n_in,
                              void* d_out, int out_size, void* d_ws, size_t ws_size,
                              hipStream_t stream) {
  const void* x     = d_in[0];
  const void* eWih0 = d_in[1];
  const void* eWhh0 = d_in[2];
  const void* eb0   = d_in[3];
  const void* eWih1 = d_in[4];
  const void* eWhh1 = d_in[5];
  const void* eb1   = d_in[6];
  const void* dWih0 = d_in[7];
  const void* dWhh0 = d_in[8];
  const void* db0   = d_in[9];
  const void* dWih1 = d_in[10];
  const void* dWhh1 = d_in[11];
  const void* db1   = d_in[12];
  const void* aW    = d_in[13];
  const void* aV    = d_in[14];
  const void* qW    = d_in[15];
  const void* qb    = d_in[16];

  char* wsb = (char*)d_ws;
  u16*   H0    = (u16*)(wsb + 0);              // [2][256][256] u16 = 262144 B
  u16*   H1    = (u16*)(wsb + 262144);         // 262144 -> 524288
  int*   sentE = (int*)(wsb + 524288);         // [16][16] = 1024 -> 525312
  int*   sentD = (int*)(wsb + 525312);         // 1024 -> 526336
  int*   flag  = (int*)(wsb + 526336);         // 256  -> 526592
  u64*   dinpG = (u64*)(wsb + 526592);         // [2][256] u64 = 4096 -> 530688
  float* ctx   = (float*)(wsb + 530688);       // 262144 -> 792832
  u32*   H0d   = (u32*)(wsb + 792832);         // [2][256][256] u32 = 524288 -> 1317120
  u32*   H1d   = (u32*)(wsb + 1317120);        // 524288 -> 1841408
  // total ws: 1,841,408 bytes

  // zero H0/H1 (h[-1]=0 data) + sentinels + flag + dinpG (stale tags never match)
  hipMemsetAsync(wsb, 0, 530688, stream);

  sniff_kernel<<<1, 256, 0, stream>>>((const u16*)eWhh0, flag);
  enc_kernel<<<256, 256, 0, stream>>>(x, eWih0, eWhh0, eb0, eWih1, eWhh1, eb1,
                                      aW, aV, H0, H1, ctx, sentE, flag);
  dec_kernel<<<256, 256, 0, stream>>>(x, dWih0, dWhh0, db0, dWih1, dWhh1, db1,
                                      qW, qb, ctx, H0d, H1d, dinpG,
                                      d_out, sentD, flag);
}